// Round 1
// baseline (5574.395 us; speedup 1.0000x reference)
//
#include <hip/hip_runtime.h>
#include <math.h>

#define BB 256
#define SS 2048
#define EE 64
#define HH 128
#define FH 512   // 4*H

// One workgroup per batch element. 512 threads: thread j owns output row j of
// the fused [4H x H] recurrent matvec (W_all row in 128 VGPRs) and row j of
// U_all (64 VGPRs), plus a 32-wide segment of W_d row (j&127) (32 VGPRs).
// h, c live in LDS; reads are wave-broadcast (same address across lanes).
// x[b,s,:] and dt[b,s] are block-uniform -> scalar loads (s_load) by compiler.
__global__ __launch_bounds__(512) void tlstm_kernel(
    const float* __restrict__ inputs,        // [B,S,E]
    const float* __restrict__ time_interval, // [B,S]
    const float* __restrict__ W_all,         // [4H,H]
    const float* __restrict__ b_all,         // [4H]
    const float* __restrict__ U_all,         // [4H,E]
    const float* __restrict__ b_u,           // [4H]
    const float* __restrict__ W_d,           // [H,H]
    const float* __restrict__ b_d,           // [H]
    const float* __restrict__ W_out,         // [1,H]
    const float* __restrict__ b_out,         // [1]
    float* __restrict__ out)                 // [B]
{
    const int b   = blockIdx.x;
    const int tid = threadIdx.x;

    __shared__ float sh_h[HH];
    __shared__ float sh_c[HH];
    __shared__ float sh_outs[FH];
    __shared__ float sh_pd[4][HH];
    __shared__ float sh_red[HH];

    // ---- load per-thread weights into registers (once) ----
    float wa[HH];   // W_all[tid][0:128]
    float ua[EE];   // U_all[tid][0:64]
    float wd[32];   // W_d[tid&127][(tid>>7)*32 : +32]

    const int r   = tid & (HH - 1);
    const int seg = tid >> 7;   // 0..3

    {
        const float4* p = (const float4*)(W_all + (size_t)tid * HH);
        #pragma unroll
        for (int i = 0; i < HH / 4; ++i) {
            float4 v = p[i];
            wa[4*i] = v.x; wa[4*i+1] = v.y; wa[4*i+2] = v.z; wa[4*i+3] = v.w;
        }
        const float4* q = (const float4*)(U_all + (size_t)tid * EE);
        #pragma unroll
        for (int i = 0; i < EE / 4; ++i) {
            float4 v = q[i];
            ua[4*i] = v.x; ua[4*i+1] = v.y; ua[4*i+2] = v.z; ua[4*i+3] = v.w;
        }
        const float4* w = (const float4*)(W_d + (size_t)r * HH + seg * 32);
        #pragma unroll
        for (int i = 0; i < 8; ++i) {
            float4 v = w[i];
            wd[4*i] = v.x; wd[4*i+1] = v.y; wd[4*i+2] = v.z; wd[4*i+3] = v.w;
        }
    }

    const float bias_j = b_all[tid] + b_u[tid];
    const float bd_r   = b_d[r];

    if (tid < HH) { sh_h[tid] = 0.0f; sh_c[tid] = 0.0f; }
    float hsum = 0.0f;   // meaningful for tid < 128
    __syncthreads();

    const float* xrow = inputs        + (size_t)b * SS * EE;
    const float* drow = time_interval + (size_t)b * SS;

    for (int s = 0; s < SS; ++s) {
        // ---- stage 1: W_d partial dot (reads c from previous step) ----
        float pd = 0.0f;
        {
            const float4* cseg = (const float4*)(sh_c + seg * 32);
            #pragma unroll
            for (int i = 0; i < 8; ++i) {
                float4 cv = cseg[i];
                pd += wd[4*i]*cv.x + wd[4*i+1]*cv.y + wd[4*i+2]*cv.z + wd[4*i+3]*cv.w;
            }
        }
        sh_pd[seg][r] = pd;

        // ---- stage 2: fused gate matvec (reads h from LDS, x via s_load) ----
        float acc = bias_j;
        {
            const float4* hp = (const float4*)sh_h;
            #pragma unroll
            for (int i = 0; i < HH / 4; ++i) {
                float4 hv = hp[i];
                acc += wa[4*i]*hv.x + wa[4*i+1]*hv.y + wa[4*i+2]*hv.z + wa[4*i+3]*hv.w;
            }
            const float* xp = xrow + (size_t)s * EE;   // block-uniform address
            #pragma unroll
            for (int e = 0; e < EE; ++e) acc += ua[e] * xp[e];
        }
        sh_outs[tid] = acc;
        __syncthreads();

        // ---- stage 3: gates + state update (threads 0..127) ----
        if (tid < HH) {
            float d   = drow[s];  // uniform
            float cs1 = tanhf(bd_r + sh_pd[0][tid] + sh_pd[1][tid]
                                   + sh_pd[2][tid] + sh_pd[3][tid]);
            float c_old = sh_c[tid];
            float c_adj = c_old + cs1 * (d - 1.0f);
            float f  = 1.0f / (1.0f + __expf(-sh_outs[tid]));
            float ii = 1.0f / (1.0f + __expf(-sh_outs[tid + HH]));
            float o  = 1.0f / (1.0f + __expf(-sh_outs[tid + 2*HH]));
            float ct = 1.0f / (1.0f + __expf(-sh_outs[tid + 3*HH]));
            float cn = f * c_adj + ii * ct;
            float hn = o * tanhf(cn);
            sh_c[tid] = cn;
            sh_h[tid] = hn;
            hsum += hn;
        }
        __syncthreads();
    }

    // ---- epilogue: out[b] = (sum_s h_s) . W_out + S*b_out ----
    if (tid < HH) sh_red[tid] = hsum * W_out[tid];
    __syncthreads();
    if (tid == 0) {
        float t = 0.0f;
        for (int i = 0; i < HH; ++i) t += sh_red[i];
        out[b] = t + (float)SS * b_out[0];
    }
}

extern "C" void kernel_launch(void* const* d_in, const int* in_sizes, int n_in,
                              void* d_out, int out_size, void* d_ws, size_t ws_size,
                              hipStream_t stream) {
    const float* inputs        = (const float*)d_in[0];
    const float* time_interval = (const float*)d_in[1];
    const float* W_all         = (const float*)d_in[2];
    const float* b_all         = (const float*)d_in[3];
    const float* U_all         = (const float*)d_in[4];
    const float* b_u           = (const float*)d_in[5];
    const float* W_d           = (const float*)d_in[6];
    const float* b_d           = (const float*)d_in[7];
    const float* W_out         = (const float*)d_in[8];
    const float* b_out         = (const float*)d_in[9];
    float* out = (float*)d_out;

    tlstm_kernel<<<dim3(BB), dim3(512), 0, stream>>>(
        inputs, time_interval, W_all, b_all, U_all, b_u,
        W_d, b_d, W_out, b_out, out);
}

// Round 2
// 4633.247 us; speedup vs baseline: 1.2031x; 1.2031x over previous
//
#include <hip/hip_runtime.h>
#include <math.h>

#define BB 256
#define SS 2048
#define EE 64
#define HH 128
#define FH 512   // 4*H

__device__ __forceinline__ float fast_sigmoid(float x) {
    return 1.0f / (1.0f + __expf(-x));
}
__device__ __forceinline__ float fast_tanh(float x) {
    x = fminf(15.0f, fmaxf(-15.0f, x));
    float e = __expf(2.0f * x);
    return (e - 1.0f) / (e + 1.0f);
}

// ---------------- Kernel 1: x_proj chunk = inputs @ U_all.T + b_u ----------------
// grid: (SL/64, B), block 512. Thread tid owns output column f = tid.
// Writes xp[b][sl][f], chunk-local sl in [0, SL).
__global__ __launch_bounds__(512) void xproj_kernel(
    const float* __restrict__ inputs,   // [B,S,E]
    const float* __restrict__ U_all,    // [4H,E]
    const float* __restrict__ b_u,      // [4H]
    float* __restrict__ xp,             // [B,SL,FH]
    int s0, int SL)
{
    const int tid = threadIdx.x;
    const int b   = blockIdx.y;
    const int st  = blockIdx.x * 64;           // chunk-local tile start

    __shared__ float xt[64 * EE];              // 16 KB

    // cooperative tile load: 4096 floats = 1024 float4, 2 per thread
    {
        const float4* src = (const float4*)(inputs + ((size_t)b * SS + (s0 + st)) * EE);
        float4* dst = (float4*)xt;
        dst[tid]       = src[tid];
        dst[tid + 512] = src[tid + 512];
    }

    // U_all row f=tid into registers
    float ua[EE];
    {
        const float4* q = (const float4*)(U_all + (size_t)tid * EE);
        #pragma unroll
        for (int i = 0; i < EE / 4; ++i) {
            float4 v = q[i];
            ua[4*i] = v.x; ua[4*i+1] = v.y; ua[4*i+2] = v.z; ua[4*i+3] = v.w;
        }
    }
    const float bias = b_u[tid];
    __syncthreads();

    float* outbase = xp + ((size_t)b * SL + st) * FH + tid;
    for (int r = 0; r < 64; ++r) {
        const float4* xv4 = (const float4*)(xt + r * EE);
        float a0 = 0.f, a1 = 0.f;
        #pragma unroll
        for (int i = 0; i < EE / 8; ++i) {
            float4 v0 = xv4[2*i], v1 = xv4[2*i+1];
            a0 += ua[8*i  ]*v0.x + ua[8*i+1]*v0.y + ua[8*i+2]*v0.z + ua[8*i+3]*v0.w;
            a1 += ua[8*i+4]*v1.x + ua[8*i+5]*v1.y + ua[8*i+6]*v1.z + ua[8*i+7]*v1.w;
        }
        outbase[(size_t)r * FH] = a0 + a1 + bias;
    }
}

// ---------------- Kernel 2: recurrent chunk ----------------
// One block per batch element, 512 threads. Thread tid owns W_all row tid
// (128 regs) + a 32-wide segment of W_d row (tid&127). State (h,c,hsum)
// persists in ws between chunks.
__global__ __launch_bounds__(512, 2) void tlstm_rec_kernel(
    const float* __restrict__ xp,            // [B,SL,FH] (b_u folded in)
    const float* __restrict__ time_interval, // [B,S]
    const float* __restrict__ W_all,         // [4H,H]
    const float* __restrict__ b_all,         // [4H]
    const float* __restrict__ W_d,           // [H,H]
    const float* __restrict__ b_d,           // [H]
    const float* __restrict__ W_out,         // [1,H]
    const float* __restrict__ b_out,         // [1]
    float* __restrict__ state,               // [3,B,H] h,c,hsum
    float* __restrict__ out,                 // [B]
    int s0, int SL)
{
    const int b   = blockIdx.x;
    const int tid = threadIdx.x;
    const int r   = tid & (HH - 1);
    const int seg = tid >> 7;     // 0..3

    __shared__ float sh_h[HH];
    __shared__ float sh_c[HH];
    __shared__ float sh_g[FH];
    __shared__ float sh_pd[HH][4];
    __shared__ float sh_red[HH];

    // ---- weights into registers ----
    float wa[HH];   // W_all[tid][:]
    float wd[32];   // W_d[r][seg*32 : +32]
    {
        const float4* p = (const float4*)(W_all + (size_t)tid * HH);
        #pragma unroll
        for (int i = 0; i < HH / 4; ++i) {
            float4 v = p[i];
            wa[4*i] = v.x; wa[4*i+1] = v.y; wa[4*i+2] = v.z; wa[4*i+3] = v.w;
        }
        const float4* w = (const float4*)(W_d + (size_t)r * HH + seg * 32);
        #pragma unroll
        for (int i = 0; i < 8; ++i) {
            float4 v = w[i];
            wd[4*i] = v.x; wd[4*i+1] = v.y; wd[4*i+2] = v.z; wd[4*i+3] = v.w;
        }
    }
    const float bias_j = b_all[tid];
    const float bd_r   = b_d[r];

    float* st_h = state + (size_t)b * HH;
    float* st_c = state + (size_t)(BB + b) * HH;
    float* st_s = state + (size_t)(2 * BB + b) * HH;

    float hsum = 0.0f;
    if (tid < HH) {
        if (s0 == 0) { sh_h[tid] = 0.f; sh_c[tid] = 0.f; }
        else { sh_h[tid] = st_h[tid]; sh_c[tid] = st_c[tid]; hsum = st_s[tid]; }
    }
    __syncthreads();

    const float* xrow = xp + (size_t)b * SL * FH;
    const float* drow = time_interval + (size_t)b * SS + s0;

    float xv    = xrow[tid];
    float dcur  = drow[0];

    for (int sl = 0; sl < SL; ++sl) {
        float xv_next = 0.f, dnext = 0.f;
        if (sl + 1 < SL) {
            xv_next = xrow[(size_t)(sl + 1) * FH + tid];
            dnext   = drow[sl + 1];
        }

        // ---- stage 1: W_d partial dot on c ----
        {
            const float4* cseg = (const float4*)(sh_c + seg * 32);
            float p0 = 0.f, p1 = 0.f;
            #pragma unroll
            for (int i = 0; i < 4; ++i) {
                float4 c0 = cseg[2*i], c1 = cseg[2*i+1];
                p0 += wd[8*i  ]*c0.x + wd[8*i+1]*c0.y + wd[8*i+2]*c0.z + wd[8*i+3]*c0.w;
                p1 += wd[8*i+4]*c1.x + wd[8*i+5]*c1.y + wd[8*i+6]*c1.z + wd[8*i+7]*c1.w;
            }
            sh_pd[r][seg] = p0 + p1;
        }

        // ---- stage 2: gate matvec + sigmoid ----
        {
            const float4* hp = (const float4*)sh_h;
            float a0 = 0.f, a1 = 0.f, a2 = 0.f, a3 = 0.f;
            #pragma unroll
            for (int i = 0; i < 8; ++i) {
                float4 h0 = hp[4*i], h1 = hp[4*i+1], h2 = hp[4*i+2], h3 = hp[4*i+3];
                a0 += wa[16*i   ]*h0.x + wa[16*i+1 ]*h0.y + wa[16*i+2 ]*h0.z + wa[16*i+3 ]*h0.w;
                a1 += wa[16*i+4 ]*h1.x + wa[16*i+5 ]*h1.y + wa[16*i+6 ]*h1.z + wa[16*i+7 ]*h1.w;
                a2 += wa[16*i+8 ]*h2.x + wa[16*i+9 ]*h2.y + wa[16*i+10]*h2.z + wa[16*i+11]*h2.w;
                a3 += wa[16*i+12]*h3.x + wa[16*i+13]*h3.y + wa[16*i+14]*h3.z + wa[16*i+15]*h3.w;
            }
            float acc = bias_j + xv + ((a0 + a1) + (a2 + a3));
            sh_g[tid] = fast_sigmoid(acc);
        }
        __syncthreads();

        // ---- stage 3: state update (threads 0..127) ----
        if (tid < HH) {
            float4 pdv = *(const float4*)&sh_pd[tid][0];
            float cs1  = fast_tanh(bd_r + ((pdv.x + pdv.y) + (pdv.z + pdv.w)));
            float c_old = sh_c[tid];
            float c_adj = c_old + cs1 * (dcur - 1.0f);
            float f  = sh_g[tid];
            float ii = sh_g[tid + HH];
            float o  = sh_g[tid + 2*HH];
            float ct = sh_g[tid + 3*HH];
            float cn = f * c_adj + ii * ct;
            float hn = o * fast_tanh(cn);
            sh_c[tid] = cn;
            sh_h[tid] = hn;
            hsum += hn;
        }
        __syncthreads();

        xv   = xv_next;
        dcur = dnext;
    }

    // ---- save state / epilogue ----
    if (tid < HH) {
        st_h[tid] = sh_h[tid];
        st_c[tid] = sh_c[tid];
        st_s[tid] = hsum;
    }
    if (s0 + SL == SS) {
        if (tid < HH) sh_red[tid] = hsum * W_out[tid];
        __syncthreads();
        if (tid == 0) {
            float t = 0.f;
            for (int i = 0; i < HH; ++i) t += sh_red[i];
            out[b] = t + (float)SS * b_out[0];
        }
    }
}

// ---------------- Fused fallback (tiny workspace): round-1 structure + fixes ----
__global__ __launch_bounds__(512, 2) void tlstm_fused_kernel(
    const float* __restrict__ inputs,        // [B,S,E]
    const float* __restrict__ time_interval, // [B,S]
    const float* __restrict__ W_all, const float* __restrict__ b_all,
    const float* __restrict__ U_all, const float* __restrict__ b_u,
    const float* __restrict__ W_d,   const float* __restrict__ b_d,
    const float* __restrict__ W_out, const float* __restrict__ b_out,
    float* __restrict__ out)
{
    const int b   = blockIdx.x;
    const int tid = threadIdx.x;
    const int r   = tid & (HH - 1);
    const int seg = tid >> 7;

    __shared__ float sh_h[HH];
    __shared__ float sh_c[HH];
    __shared__ float sh_g[FH];
    __shared__ float sh_pd[HH][4];
    __shared__ float sh_red[HH];

    float wa[HH], ua[EE], wd[32];
    {
        const float4* p = (const float4*)(W_all + (size_t)tid * HH);
        #pragma unroll
        for (int i = 0; i < HH / 4; ++i) { float4 v = p[i]; wa[4*i]=v.x; wa[4*i+1]=v.y; wa[4*i+2]=v.z; wa[4*i+3]=v.w; }
        const float4* q = (const float4*)(U_all + (size_t)tid * EE);
        #pragma unroll
        for (int i = 0; i < EE / 4; ++i) { float4 v = q[i]; ua[4*i]=v.x; ua[4*i+1]=v.y; ua[4*i+2]=v.z; ua[4*i+3]=v.w; }
        const float4* w = (const float4*)(W_d + (size_t)r * HH + seg * 32);
        #pragma unroll
        for (int i = 0; i < 8; ++i) { float4 v = w[i]; wd[4*i]=v.x; wd[4*i+1]=v.y; wd[4*i+2]=v.z; wd[4*i+3]=v.w; }
    }
    const float bias_j = b_all[tid] + b_u[tid];
    const float bd_r   = b_d[r];

    if (tid < HH) { sh_h[tid] = 0.f; sh_c[tid] = 0.f; }
    float hsum = 0.f;
    __syncthreads();

    const float* xrow = inputs + (size_t)b * SS * EE;
    const float* drow = time_interval + (size_t)b * SS;

    for (int s = 0; s < SS; ++s) {
        float dcur = drow[s];
        {
            const float4* cseg = (const float4*)(sh_c + seg * 32);
            float p0 = 0.f, p1 = 0.f;
            #pragma unroll
            for (int i = 0; i < 4; ++i) {
                float4 c0 = cseg[2*i], c1 = cseg[2*i+1];
                p0 += wd[8*i  ]*c0.x + wd[8*i+1]*c0.y + wd[8*i+2]*c0.z + wd[8*i+3]*c0.w;
                p1 += wd[8*i+4]*c1.x + wd[8*i+5]*c1.y + wd[8*i+6]*c1.z + wd[8*i+7]*c1.w;
            }
            sh_pd[r][seg] = p0 + p1;
        }
        {
            const float4* hp = (const float4*)sh_h;
            float a0=0.f,a1=0.f,a2=0.f,a3=0.f;
            #pragma unroll
            for (int i = 0; i < 8; ++i) {
                float4 h0=hp[4*i], h1=hp[4*i+1], h2=hp[4*i+2], h3=hp[4*i+3];
                a0 += wa[16*i   ]*h0.x + wa[16*i+1 ]*h0.y + wa[16*i+2 ]*h0.z + wa[16*i+3 ]*h0.w;
                a1 += wa[16*i+4 ]*h1.x + wa[16*i+5 ]*h1.y + wa[16*i+6 ]*h1.z + wa[16*i+7 ]*h1.w;
                a2 += wa[16*i+8 ]*h2.x + wa[16*i+9 ]*h2.y + wa[16*i+10]*h2.z + wa[16*i+11]*h2.w;
                a3 += wa[16*i+12]*h3.x + wa[16*i+13]*h3.y + wa[16*i+14]*h3.z + wa[16*i+15]*h3.w;
            }
            const float* xptr = xrow + (size_t)s * EE;
            float ax = 0.f;
            #pragma unroll
            for (int e = 0; e < EE; ++e) ax += ua[e] * xptr[e];
            sh_g[tid] = fast_sigmoid(bias_j + ax + ((a0+a1)+(a2+a3)));
        }
        __syncthreads();
        if (tid < HH) {
            float4 pdv = *(const float4*)&sh_pd[tid][0];
            float cs1 = fast_tanh(bd_r + ((pdv.x+pdv.y)+(pdv.z+pdv.w)));
            float c_adj = sh_c[tid] + cs1 * (dcur - 1.0f);
            float f = sh_g[tid], ii = sh_g[tid+HH], o = sh_g[tid+2*HH], ct = sh_g[tid+3*HH];
            float cn = f * c_adj + ii * ct;
            float hn = o * fast_tanh(cn);
            sh_c[tid] = cn; sh_h[tid] = hn; hsum += hn;
        }
        __syncthreads();
    }
    if (tid < HH) sh_red[tid] = hsum * W_out[tid];
    __syncthreads();
    if (tid == 0) {
        float t = 0.f;
        for (int i = 0; i < HH; ++i) t += sh_red[i];
        out[b] = t + (float)SS * b_out[0];
    }
}

extern "C" void kernel_launch(void* const* d_in, const int* in_sizes, int n_in,
                              void* d_out, int out_size, void* d_ws, size_t ws_size,
                              hipStream_t stream) {
    const float* inputs        = (const float*)d_in[0];
    const float* time_interval = (const float*)d_in[1];
    const float* W_all         = (const float*)d_in[2];
    const float* b_all         = (const float*)d_in[3];
    const float* U_all         = (const float*)d_in[4];
    const float* b_u           = (const float*)d_in[5];
    const float* W_d           = (const float*)d_in[6];
    const float* b_d           = (const float*)d_in[7];
    const float* W_out         = (const float*)d_in[8];
    const float* b_out         = (const float*)d_in[9];
    float* out = (float*)d_out;

    const size_t STATE_BYTES = (size_t)3 * BB * HH * sizeof(float);
    int SL = 0;
    for (int cand = SS; cand >= 64; cand >>= 1) {
        if ((size_t)BB * cand * FH * sizeof(float) + STATE_BYTES <= ws_size) { SL = cand; break; }
    }

    if (SL > 0) {
        float* xp    = (float*)d_ws;
        float* state = xp + (size_t)BB * SL * FH;
        for (int s0 = 0; s0 < SS; s0 += SL) {
            xproj_kernel<<<dim3(SL / 64, BB), dim3(512), 0, stream>>>(
                inputs, U_all, b_u, xp, s0, SL);
            tlstm_rec_kernel<<<dim3(BB), dim3(512), 0, stream>>>(
                xp, time_interval, W_all, b_all, W_d, b_d, W_out, b_out,
                state, out, s0, SL);
        }
    } else {
        tlstm_fused_kernel<<<dim3(BB), dim3(512), 0, stream>>>(
            inputs, time_interval, W_all, b_all, U_all, b_u,
            W_d, b_d, W_out, b_out, out);
    }
}

// Round 3
// 4584.586 us; speedup vs baseline: 1.2159x; 1.0106x over previous
//
#include <hip/hip_runtime.h>
#include <math.h>

#define BB 256
#define SS 2048
#define EE 64
#define HH 128
#define FH 512   // 4*H

typedef _Float16 half2_t __attribute__((ext_vector_type(2)));

#if defined(__has_builtin)
#if __has_builtin(__builtin_amdgcn_fdot2)
#define HAVE_FDOT2 1
#endif
#endif

__device__ __forceinline__ float dot2f(half2_t a, half2_t b, float c) {
#ifdef HAVE_FDOT2
    return __builtin_amdgcn_fdot2(a, b, c, false);
#else
    return c + (float)a.x * (float)b.x + (float)a.y * (float)b.y;
#endif
}

__device__ __forceinline__ float fast_sigmoid(float x) {
    return 1.0f / (1.0f + __expf(-x));
}
__device__ __forceinline__ float fast_tanh(float x) {
    x = fminf(15.0f, fmaxf(-15.0f, x));
    float e = __expf(2.0f * x);
    return (e - 1.0f) / (e + 1.0f);
}

// padded c index: slice bases land on distinct banks
#define CPAD(k) ((k) + ((((k) >> 5)) << 2))

// ---------------- Kernel 1: x_proj = inputs @ U_all.T + b_u ----------------
// 512 threads; thread owns column f = tid (ua[64] pinned in VGPRs).
// x rows are block-uniform -> scalar (SGPR) loads. 64 s-rows per block.
__global__ __launch_bounds__(512) __attribute__((amdgpu_waves_per_eu(2, 4)))
void xproj_kernel(
    const float* __restrict__ inputs,   // [B,S,E]
    const float* __restrict__ U_all,    // [4H,E]
    const float* __restrict__ b_u,      // [4H]
    float* __restrict__ xp,             // [B,SL,FH]
    int s0, int SL)
{
    const int t  = threadIdx.x;
    const int b  = blockIdx.y;
    const int st = blockIdx.x * 64;

    float ua[EE];
    {
        const float4* q = (const float4*)(U_all + (size_t)t * EE);
        #pragma unroll
        for (int i = 0; i < EE / 4; ++i) {
            float4 v = q[i];
            ua[4*i] = v.x; ua[4*i+1] = v.y; ua[4*i+2] = v.z; ua[4*i+3] = v.w;
        }
    }
    #pragma unroll
    for (int i = 0; i < EE; ++i) asm volatile("" : "+v"(ua[i]));

    const float bias = b_u[t];
    const float* xbase = inputs + ((size_t)b * SS + (s0 + st)) * EE;
    float* obase = xp + ((size_t)b * SL + st) * FH + t;

    for (int r = 0; r < 64; ++r) {
        const float* xr = xbase + (size_t)r * EE;   // uniform address -> s_load
        float a0 = 0.f, a1 = 0.f;
        #pragma unroll
        for (int e = 0; e < EE; e += 2) {
            a0 += ua[e]     * xr[e];
            a1 += ua[e + 1] * xr[e + 1];
        }
        obase[(size_t)r * FH] = a0 + a1 + bias;
    }
}

// ---------------- Kernel 2: recurrent chunk ----------------
// One block per batch element, 512 threads. Group of 4 lanes per hidden unit:
// g = t>>2 (0..127), sub = t&3, k-slice = [sub*32, sub*32+32).
// Each lane: 4 gate rows as packed fp16 (64 VGPRs) + W_d row slice fp32 (32).
// Butterfly-reduce partials over the 4 lanes; all lanes redundantly compute
// the epilogue; sub==0 writes state. h stored fp16 in LDS, c stays fp32.
// Double-buffered h/c -> single barrier per step.
__global__ __launch_bounds__(512) __attribute__((amdgpu_waves_per_eu(2, 2)))
void tlstm_rec_kernel(
    const float* __restrict__ xp,            // [B,SL,FH] (b_u folded in)
    const float* __restrict__ time_interval, // [B,S]
    const float* __restrict__ W_all,         // [4H,H]
    const float* __restrict__ b_all,         // [4H]
    const float* __restrict__ W_d,           // [H,H]
    const float* __restrict__ b_d,           // [H]
    const float* __restrict__ W_out,         // [1,H]
    const float* __restrict__ b_out,         // [1]
    float* __restrict__ state,               // [3,B,H] h,c,hsum
    float* __restrict__ out,                 // [B]
    int s0, int SL)
{
    const int b   = blockIdx.x;
    const int t   = threadIdx.x;
    const int g   = t >> 2;     // 0..127
    const int sub = t & 3;      // 0..3
    const int k0  = sub * 32;

    __shared__ half2_t sh_h2[2][64];
    __shared__ float   sh_c[2][144];    // padded (CPAD max 139)
    __shared__ float   sh_red[HH];

    // ---- weights into registers (packed fp16 gates + fp32 W_d slice) ----
    half2_t wg[4][16];
    float   wd[32];
    float   bq[4];
    {
        #pragma unroll
        for (int q = 0; q < 4; ++q) {
            const float4* p = (const float4*)(W_all + (size_t)(g + 128 * q) * HH + k0);
            #pragma unroll
            for (int i = 0; i < 8; ++i) {
                float4 v = p[i];
                half2_t h0, h1;
                h0.x = (_Float16)v.x; h0.y = (_Float16)v.y;
                h1.x = (_Float16)v.z; h1.y = (_Float16)v.w;
                wg[q][2*i]   = h0;
                wg[q][2*i+1] = h1;
            }
            bq[q] = b_all[g + 128 * q];
        }
        const float4* p = (const float4*)(W_d + (size_t)g * HH + k0);
        #pragma unroll
        for (int i = 0; i < 8; ++i) {
            float4 v = p[i];
            wd[4*i] = v.x; wd[4*i+1] = v.y; wd[4*i+2] = v.z; wd[4*i+3] = v.w;
        }
    }
    #pragma unroll
    for (int q = 0; q < 4; ++q)
        #pragma unroll
        for (int i = 0; i < 16; ++i) asm volatile("" : "+v"(wg[q][i]));
    #pragma unroll
    for (int i = 0; i < 32; ++i) asm volatile("" : "+v"(wd[i]));

    const float bd_r = b_d[g];

    float* st_h = state + (size_t)b * HH;
    float* st_c = state + (size_t)(BB + b) * HH;
    float* st_s = state + (size_t)(2 * BB + b) * HH;

    // ---- init state into buffer 0 ----
    if (t < 64) {
        half2_t hv;
        if (s0 == 0) { hv.x = (_Float16)0.f; hv.y = (_Float16)0.f; }
        else { hv.x = (_Float16)st_h[2*t]; hv.y = (_Float16)st_h[2*t+1]; }
        sh_h2[0][t] = hv;
    }
    if (t < HH) sh_c[0][CPAD(t)] = (s0 == 0) ? 0.f : st_c[t];
    float hsum = (s0 == 0) ? 0.f : st_s[g];
    float hn_keep = 0.f, cn_keep = 0.f;
    __syncthreads();

    const float* xrow = xp + (size_t)b * SL * FH;
    const float* drow = time_interval + (size_t)b * SS + s0;

    float xv0 = xrow[g], xv1 = xrow[g + 128], xv2 = xrow[g + 256], xv3 = xrow[g + 384];
    float dcur = drow[0];

    for (int sl = 0; sl < SL; ++sl) {
        const int cur = sl & 1, nxt = cur ^ 1;

        float xn0 = 0.f, xn1 = 0.f, xn2 = 0.f, xn3 = 0.f, dnext = 0.f;
        if (sl + 1 < SL) {
            const float* xnp = xrow + (size_t)(sl + 1) * FH + g;
            xn0 = xnp[0]; xn1 = xnp[128]; xn2 = xnp[256]; xn3 = xnp[384];
            dnext = drow[sl + 1];
        }

        // ---- gate partial dots (fp16 dot2) + W_d partial dot (fp32) ----
        float a0 = 0.f, a1 = 0.f, a2 = 0.f, a3 = 0.f, ad = 0.f;
        {
            const half2_t* hp = &sh_h2[cur][sub * 16];
            #pragma unroll
            for (int i = 0; i < 16; ++i) {
                half2_t hv = hp[i];
                a0 = dot2f(wg[0][i], hv, a0);
                a1 = dot2f(wg[1][i], hv, a1);
                a2 = dot2f(wg[2][i], hv, a2);
                a3 = dot2f(wg[3][i], hv, a3);
            }
            const float4* cp = (const float4*)&sh_c[cur][36 * sub];
            #pragma unroll
            for (int i = 0; i < 8; ++i) {
                float4 cv = cp[i];
                ad += wd[4*i]*cv.x + wd[4*i+1]*cv.y + wd[4*i+2]*cv.z + wd[4*i+3]*cv.w;
            }
        }

        // ---- butterfly over the 4 sub-lanes ----
        a0 += __shfl_xor(a0, 1); a1 += __shfl_xor(a1, 1);
        a2 += __shfl_xor(a2, 1); a3 += __shfl_xor(a3, 1);
        ad += __shfl_xor(ad, 1);
        a0 += __shfl_xor(a0, 2); a1 += __shfl_xor(a1, 2);
        a2 += __shfl_xor(a2, 2); a3 += __shfl_xor(a3, 2);
        ad += __shfl_xor(ad, 2);

        // ---- epilogue (all 4 lanes redundantly; sub==0 stores) ----
        float c_old = sh_c[cur][CPAD(g)];
        float cs1   = fast_tanh(bd_r + ad);
        float c_adj = c_old + cs1 * (dcur - 1.0f);
        float f  = fast_sigmoid(a0 + bq[0] + xv0);
        float ii = fast_sigmoid(a1 + bq[1] + xv1);
        float o  = fast_sigmoid(a2 + bq[2] + xv2);
        float ct = fast_sigmoid(a3 + bq[3] + xv3);
        float cn = f * c_adj + ii * ct;
        float hn = o * fast_tanh(cn);
        if (sub == 0) {
            sh_c[nxt][CPAD(g)] = cn;
            ((_Float16*)sh_h2[nxt])[g] = (_Float16)hn;
        }
        hsum += hn;
        hn_keep = hn; cn_keep = cn;
        __syncthreads();

        xv0 = xn0; xv1 = xn1; xv2 = xn2; xv3 = xn3;
        dcur = dnext;
    }

    // ---- save state ----
    if (sub == 0) {
        st_h[g] = hn_keep;
        st_c[g] = cn_keep;
        st_s[g] = hsum;
    }

    // ---- final output epilogue ----
    if (s0 + SL == SS) {
        if (sub == 0) sh_red[g] = hsum * W_out[g];
        __syncthreads();
        if (t == 0) {
            float s = 0.f;
            for (int i = 0; i < HH; ++i) s += sh_red[i];
            out[b] = s + (float)SS * b_out[0];
        }
    }
}

// ---------------- Fused fallback (tiny workspace): round-2 fp32 path ----
__global__ __launch_bounds__(512, 2) void tlstm_fused_kernel(
    const float* __restrict__ inputs,
    const float* __restrict__ time_interval,
    const float* __restrict__ W_all, const float* __restrict__ b_all,
    const float* __restrict__ U_all, const float* __restrict__ b_u,
    const float* __restrict__ W_d,   const float* __restrict__ b_d,
    const float* __restrict__ W_out, const float* __restrict__ b_out,
    float* __restrict__ out)
{
    const int b   = blockIdx.x;
    const int tid = threadIdx.x;
    const int r   = tid & (HH - 1);
    const int seg = tid >> 7;

    __shared__ float sh_h[HH];
    __shared__ float sh_c[HH];
    __shared__ float sh_g[FH];
    __shared__ float sh_pd[HH][4];
    __shared__ float sh_red[HH];

    float wa[HH], ua[EE], wd[32];
    {
        const float4* p = (const float4*)(W_all + (size_t)tid * HH);
        #pragma unroll
        for (int i = 0; i < HH / 4; ++i) { float4 v = p[i]; wa[4*i]=v.x; wa[4*i+1]=v.y; wa[4*i+2]=v.z; wa[4*i+3]=v.w; }
        const float4* q = (const float4*)(U_all + (size_t)tid * EE);
        #pragma unroll
        for (int i = 0; i < EE / 4; ++i) { float4 v = q[i]; ua[4*i]=v.x; ua[4*i+1]=v.y; ua[4*i+2]=v.z; ua[4*i+3]=v.w; }
        const float4* w = (const float4*)(W_d + (size_t)r * HH + seg * 32);
        #pragma unroll
        for (int i = 0; i < 8; ++i) { float4 v = w[i]; wd[4*i]=v.x; wd[4*i+1]=v.y; wd[4*i+2]=v.z; wd[4*i+3]=v.w; }
    }
    const float bias_j = b_all[tid] + b_u[tid];
    const float bd_r   = b_d[r];

    if (tid < HH) { sh_h[tid] = 0.f; sh_c[tid] = 0.f; }
    float hsum = 0.f;
    __syncthreads();

    const float* xrow = inputs + (size_t)b * SS * EE;
    const float* drow = time_interval + (size_t)b * SS;

    for (int s = 0; s < SS; ++s) {
        float dcur = drow[s];
        {
            const float4* cseg = (const float4*)(sh_c + seg * 32);
            float p0 = 0.f, p1 = 0.f;
            #pragma unroll
            for (int i = 0; i < 4; ++i) {
                float4 c0 = cseg[2*i], c1 = cseg[2*i+1];
                p0 += wd[8*i  ]*c0.x + wd[8*i+1]*c0.y + wd[8*i+2]*c0.z + wd[8*i+3]*c0.w;
                p1 += wd[8*i+4]*c1.x + wd[8*i+5]*c1.y + wd[8*i+6]*c1.z + wd[8*i+7]*c1.w;
            }
            sh_pd[r][seg] = p0 + p1;
        }
        {
            const float4* hp = (const float4*)sh_h;
            float a0=0.f,a1=0.f,a2=0.f,a3=0.f;
            #pragma unroll
            for (int i = 0; i < 8; ++i) {
                float4 h0=hp[4*i], h1=hp[4*i+1], h2=hp[4*i+2], h3=hp[4*i+3];
                a0 += wa[16*i   ]*h0.x + wa[16*i+1 ]*h0.y + wa[16*i+2 ]*h0.z + wa[16*i+3 ]*h0.w;
                a1 += wa[16*i+4 ]*h1.x + wa[16*i+5 ]*h1.y + wa[16*i+6 ]*h1.z + wa[16*i+7 ]*h1.w;
                a2 += wa[16*i+8 ]*h2.x + wa[16*i+9 ]*h2.y + wa[16*i+10]*h2.z + wa[16*i+11]*h2.w;
                a3 += wa[16*i+12]*h3.x + wa[16*i+13]*h3.y + wa[16*i+14]*h3.z + wa[16*i+15]*h3.w;
            }
            const float* xptr = xrow + (size_t)s * EE;
            float ax = 0.f;
            #pragma unroll
            for (int e = 0; e < EE; ++e) ax += ua[e] * xptr[e];
            sh_g[tid] = fast_sigmoid(bias_j + ax + ((a0+a1)+(a2+a3)));
        }
        __syncthreads();
        if (tid < HH) {
            float4 pdv = *(const float4*)&sh_pd[tid][0];
            float cs1 = fast_tanh(bd_r + ((pdv.x+pdv.y)+(pdv.z+pdv.w)));
            float c_adj = sh_c[tid] + cs1 * (dcur - 1.0f);
            float f = sh_g[tid], ii = sh_g[tid+HH], o = sh_g[tid+2*HH], ct = sh_g[tid+3*HH];
            float cn = f * c_adj + ii * ct;
            float hn = o * fast_tanh(cn);
            sh_c[tid] = cn; sh_h[tid] = hn; hsum += hn;
        }
        __syncthreads();
    }
    if (tid < HH) sh_red[tid] = hsum * W_out[tid];
    __syncthreads();
    if (tid == 0) {
        float s = 0.f;
        for (int i = 0; i < HH; ++i) s += sh_red[i];
        out[b] = s + (float)SS * b_out[0];
    }
}

extern "C" void kernel_launch(void* const* d_in, const int* in_sizes, int n_in,
                              void* d_out, int out_size, void* d_ws, size_t ws_size,
                              hipStream_t stream) {
    const float* inputs        = (const float*)d_in[0];
    const float* time_interval = (const float*)d_in[1];
    const float* W_all         = (const float*)d_in[2];
    const float* b_all         = (const float*)d_in[3];
    const float* U_all         = (const float*)d_in[4];
    const float* b_u           = (const float*)d_in[5];
    const float* W_d           = (const float*)d_in[6];
    const float* b_d           = (const float*)d_in[7];
    const float* W_out         = (const float*)d_in[8];
    const float* b_out         = (const float*)d_in[9];
    float* out = (float*)d_out;

    const size_t STATE_BYTES = (size_t)3 * BB * HH * sizeof(float);
    int SL = 0;
    for (int cand = SS; cand >= 64; cand >>= 1) {
        if ((size_t)BB * cand * FH * sizeof(float) + STATE_BYTES <= ws_size) { SL = cand; break; }
    }

    if (SL > 0) {
        float* xp    = (float*)d_ws;
        float* state = xp + (size_t)BB * SL * FH;
        for (int s0 = 0; s0 < SS; s0 += SL) {
            xproj_kernel<<<dim3(SL / 64, BB), dim3(512), 0, stream>>>(
                inputs, U_all, b_u, xp, s0, SL);
            tlstm_rec_kernel<<<dim3(BB), dim3(512), 0, stream>>>(
                xp, time_interval, W_all, b_all, W_d, b_d, W_out, b_out,
                state, out, s0, SL);
        }
    } else {
        tlstm_fused_kernel<<<dim3(BB), dim3(512), 0, stream>>>(
            inputs, time_interval, W_all, b_all, U_all, b_u,
            W_d, b_d, W_out, b_out, out);
    }
}

// Round 4
// 2712.092 us; speedup vs baseline: 2.0554x; 1.6904x over previous
//
#include <hip/hip_runtime.h>
#include <math.h>

#define BB 256
#define SS 2048
#define EE 64
#define HH 128

typedef _Float16 half2_t __attribute__((ext_vector_type(2)));

#if defined(__has_builtin)
#if __has_builtin(__builtin_amdgcn_fdot2)
#define HAVE_FDOT2 1
#endif
#endif

__device__ __forceinline__ float dot2f(half2_t a, half2_t b, float c) {
#ifdef HAVE_FDOT2
    return __builtin_amdgcn_fdot2(a, b, c, false);
#else
    return c + (float)a.x * (float)b.x + (float)a.y * (float)b.y;
#endif
}

__device__ __forceinline__ float fast_sigmoid(float x) {
    return 1.0f / (1.0f + __expf(-x));
}
__device__ __forceinline__ float fast_tanh(float x) {
    x = fminf(15.0f, fmaxf(-15.0f, x));
    float e = __expf(2.0f * x);
    return (e - 1.0f) / (e + 1.0f);
}

// fp32 c buffer: 32-float slices at stride 36 floats -> slice bases on banks 0/4/8/12
#define CPAD(k) ((k) + (((k) >> 5) << 2))
// fp16 h buffer: 32-fp16 slices at stride 40 fp16 (80 B) -> slice bases on
// dword-banks 0/20/8/28, 16B-aligned for b128 reads
#define HPADW(g) (((g) & 31) + 40 * ((g) >> 5))

// One block per batch element, 512 threads, single dispatch for all S=2048.
// Group of 4 lanes per hidden unit: g = t>>2, sub = t&3.
// Per lane (registers, pinned):
//   wg[4][16] half2 : W_all rows {g,g+128,g+256,g+384}, k-slice [32*sub,+32)
//   ug[4][8]  half2 : U_all rows (same),               e-slice [16*sub,+16)
//   wd[32]    fp32  : W_d row g,                       k-slice [32*sub,+32)
// h stored fp16 in LDS (padded), c fp32 (padded), x-row staged fp16 by wave 0
// with a 2-step global->reg->LDS pipeline. Double-buffered -> 1 barrier/step.
__global__ __launch_bounds__(512, 2) void tlstm_fused2_kernel(
    const float* __restrict__ inputs,        // [B,S,E]
    const float* __restrict__ time_interval, // [B,S]
    const float* __restrict__ W_all,         // [4H,H]
    const float* __restrict__ b_all,         // [4H]
    const float* __restrict__ U_all,         // [4H,E]
    const float* __restrict__ b_u,           // [4H]
    const float* __restrict__ W_d,           // [H,H]
    const float* __restrict__ b_d,           // [H]
    const float* __restrict__ W_out,         // [1,H]
    const float* __restrict__ b_out,         // [1]
    float* __restrict__ out)                 // [B]
{
    const int b   = blockIdx.x;
    const int t   = threadIdx.x;
    const int g   = t >> 2;     // 0..127
    const int sub = t & 3;      // 0..3

    __shared__ _Float16 sh_h[2][160];   // padded: HPADW(127)=151
    __shared__ float    sh_c[2][144];   // padded: CPAD(127)=139
    __shared__ half2_t  sh_x2[2][32];   // x row as fp16 (64 elems)
    __shared__ float    sh_red[HH];

    // ---- weights into registers ----
    half2_t wg[4][16];
    half2_t ug[4][8];
    float   wd[32];
    float   bq[4];
    {
        #pragma unroll
        for (int q = 0; q < 4; ++q) {
            const int row = g + 128 * q;
            const float4* p = (const float4*)(W_all + (size_t)row * HH + 32 * sub);
            #pragma unroll
            for (int i = 0; i < 8; ++i) {
                float4 v = p[i];
                half2_t h0, h1;
                h0.x = (_Float16)v.x; h0.y = (_Float16)v.y;
                h1.x = (_Float16)v.z; h1.y = (_Float16)v.w;
                wg[q][2*i]   = h0;
                wg[q][2*i+1] = h1;
            }
            const float4* pu = (const float4*)(U_all + (size_t)row * EE + 16 * sub);
            #pragma unroll
            for (int i = 0; i < 4; ++i) {
                float4 v = pu[i];
                half2_t h0, h1;
                h0.x = (_Float16)v.x; h0.y = (_Float16)v.y;
                h1.x = (_Float16)v.z; h1.y = (_Float16)v.w;
                ug[q][2*i]   = h0;
                ug[q][2*i+1] = h1;
            }
            bq[q] = b_all[row] + b_u[row];
        }
        const float4* p = (const float4*)(W_d + (size_t)g * HH + 32 * sub);
        #pragma unroll
        for (int i = 0; i < 8; ++i) {
            float4 v = p[i];
            wd[4*i] = v.x; wd[4*i+1] = v.y; wd[4*i+2] = v.z; wd[4*i+3] = v.w;
        }
    }
    #pragma unroll
    for (int q = 0; q < 4; ++q) {
        #pragma unroll
        for (int i = 0; i < 16; ++i) asm volatile("" : "+v"(wg[q][i]));
        #pragma unroll
        for (int i = 0; i < 8; ++i)  asm volatile("" : "+v"(ug[q][i]));
    }
    #pragma unroll
    for (int i = 0; i < 32; ++i) asm volatile("" : "+v"(wd[i]));

    const float bd_r = b_d[g];

    const float* xb   = inputs + (size_t)b * SS * EE;
    const float* drow = time_interval + (size_t)b * SS;

    // ---- prologue: x pipeline (wave 0) + zero state ----
    float xcv = 0.f, xld = 0.f;
    if (t < 64) {
        sh_h[0][t] = (_Float16)0.f;  sh_h[0][t + 80] = (_Float16)0.f; // covers pads too
        ((_Float16*)sh_x2[0])[t] = (_Float16)xb[t];   // x[0]
        xcv = xb[EE + t];                              // x[1]
        xld = xb[2 * EE + t];                          // x[2]
    }
    if (t < HH) sh_c[0][CPAD(t)] = 0.f;
    float dv0 = drow[0], dv1 = drow[1], dv2 = drow[2];
    float hsum = 0.f;
    __syncthreads();

    for (int s = 0; s < SS; ++s) {
        const int cur = s & 1, nxt = cur ^ 1;

        // ---- stage x[s+1] into LDS; advance pipeline (wave 0 only) ----
        if (t < 64) {
            ((_Float16*)sh_x2[nxt])[t] = (_Float16)xcv;
            xcv = xld;
            const int s3 = (s + 3 < SS) ? s + 3 : SS - 1;
            xld = xb[(size_t)s3 * EE + t];
        }

        // ---- gate dots (fp16 dot2: h-part + x-part) + W_d dot (fp32) ----
        float a0 = 0.f, a1 = 0.f, a2 = 0.f, a3 = 0.f, ad = 0.f;
        {
            const half2_t* hp = (const half2_t*)&sh_h[cur][40 * sub];
            #pragma unroll
            for (int i = 0; i < 16; ++i) {
                half2_t hv = hp[i];
                a0 = dot2f(wg[0][i], hv, a0);
                a1 = dot2f(wg[1][i], hv, a1);
                a2 = dot2f(wg[2][i], hv, a2);
                a3 = dot2f(wg[3][i], hv, a3);
            }
            const half2_t* xp2 = &sh_x2[cur][8 * sub];
            #pragma unroll
            for (int i = 0; i < 8; ++i) {
                half2_t xv = xp2[i];
                a0 = dot2f(ug[0][i], xv, a0);
                a1 = dot2f(ug[1][i], xv, a1);
                a2 = dot2f(ug[2][i], xv, a2);
                a3 = dot2f(ug[3][i], xv, a3);
            }
            const float4* cp = (const float4*)&sh_c[cur][36 * sub];
            #pragma unroll
            for (int i = 0; i < 8; ++i) {
                float4 cv = cp[i];
                ad += wd[4*i]*cv.x + wd[4*i+1]*cv.y + wd[4*i+2]*cv.z + wd[4*i+3]*cv.w;
            }
        }

        // ---- butterfly over the 4 sub-lanes ----
        a0 += __shfl_xor(a0, 1); a1 += __shfl_xor(a1, 1);
        a2 += __shfl_xor(a2, 1); a3 += __shfl_xor(a3, 1);
        ad += __shfl_xor(ad, 1);
        a0 += __shfl_xor(a0, 2); a1 += __shfl_xor(a1, 2);
        a2 += __shfl_xor(a2, 2); a3 += __shfl_xor(a3, 2);
        ad += __shfl_xor(ad, 2);

        // ---- epilogue (redundant across sub lanes; sub==0 stores) ----
        float c_old = sh_c[cur][CPAD(g)];
        float cs1   = fast_tanh(bd_r + ad);
        float c_adj = c_old + cs1 * (dv0 - 1.0f);
        float f  = fast_sigmoid(a0 + bq[0]);
        float ii = fast_sigmoid(a1 + bq[1]);
        float o  = fast_sigmoid(a2 + bq[2]);
        float ct = fast_sigmoid(a3 + bq[3]);
        float cn = f * c_adj + ii * ct;
        float hn = o * fast_tanh(cn);
        if (sub == 0) {
            sh_c[nxt][CPAD(g)] = cn;
            sh_h[nxt][HPADW(g)] = (_Float16)hn;
        }
        hsum += hn;

        // ---- rotate dt pipeline (uniform scalar loads) ----
        dv0 = dv1; dv1 = dv2;
        const int sd = (s + 3 < SS) ? s + 3 : SS - 1;
        dv2 = drow[sd];

        __syncthreads();
    }

    // ---- output epilogue: out[b] = (sum_s h_s) . W_out + S*b_out ----
    if (sub == 0) sh_red[g] = hsum * W_out[g];
    __syncthreads();
    if (t == 0) {
        float acc = 0.f;
        for (int i = 0; i < HH; ++i) acc += sh_red[i];
        out[b] = acc + (float)SS * b_out[0];
    }
}

extern "C" void kernel_launch(void* const* d_in, const int* in_sizes, int n_in,
                              void* d_out, int out_size, void* d_ws, size_t ws_size,
                              hipStream_t stream) {
    const float* inputs        = (const float*)d_in[0];
    const float* time_interval = (const float*)d_in[1];
    const float* W_all         = (const float*)d_in[2];
    const float* b_all         = (const float*)d_in[3];
    const float* U_all         = (const float*)d_in[4];
    const float* b_u           = (const float*)d_in[5];
    const float* W_d           = (const float*)d_in[6];
    const float* b_d           = (const float*)d_in[7];
    const float* W_out         = (const float*)d_in[8];
    const float* b_out         = (const float*)d_in[9];
    float* out = (float*)d_out;

    tlstm_fused2_kernel<<<dim3(BB), dim3(512), 0, stream>>>(
        inputs, time_interval, W_all, b_all, U_all, b_u,
        W_d, b_d, W_out, b_out, out);
}

// Round 6
// 2688.143 us; speedup vs baseline: 2.0737x; 1.0089x over previous
//
#include <hip/hip_runtime.h>
#include <math.h>

#define BB 256
#define SS 2048
#define EE 64
#define HH 128

typedef _Float16 half2_t __attribute__((ext_vector_type(2)));

#if defined(__has_builtin)
#if __has_builtin(__builtin_amdgcn_fdot2)
#define HAVE_FDOT2 1
#endif
#endif

__device__ __forceinline__ float dot2f(half2_t a, half2_t b, float c) {
#ifdef HAVE_FDOT2
    return __builtin_amdgcn_fdot2(a, b, c, false);
#else
    return c + (float)a.x * (float)b.x + (float)a.y * (float)b.y;
#endif
}

__device__ __forceinline__ float fast_sigmoid(float x) {
    return 1.0f / (1.0f + __expf(-x));
}
__device__ __forceinline__ float fast_tanh(float x) {
    x = fminf(15.0f, fmaxf(-15.0f, x));
    float e = __expf(2.0f * x);
    return (e - 1.0f) / (e + 1.0f);
}

// fp32 c buffer: 32-float slices at stride 36 floats -> slice bases on banks 0/4/8/12
#define CPAD(k) ((k) + (((k) >> 5) << 2))
// fp16 h buffer: 32-fp16 slices at stride 40 fp16 (80 B)
#define HPADW(g) (((g) & 31) + 40 * ((g) >> 5))

// One block per batch element, 512 threads, single dispatch.
// Group of 4 lanes per hidden unit: g = t>>2, sub = t&3.
// Weights loaded via VOLATILE pointers -> compiler cannot re-load them in the
// loop; values must stay register-resident.
// ROUND-5 BUG FIX: the padded h buffer has live slots up to index 151
// (HPADW(127)); the old prologue only zeroed {0..63, 80..143}, leaving
// g=56..63 and g=120..127 reading uninitialized LDS at step 0 (NaN in r5,
// absmax~1.0 in r4). Now zero all 160 entries.
__global__ __launch_bounds__(512, 2) void tlstm_fused3_kernel(
    const float* __restrict__ inputs,        // [B,S,E]
    const float* __restrict__ time_interval, // [B,S]
    const float* __restrict__ W_all,         // [4H,H]
    const float* __restrict__ b_all,         // [4H]
    const float* __restrict__ U_all,         // [4H,E]
    const float* __restrict__ b_u,           // [4H]
    const float* __restrict__ W_d,           // [H,H]
    const float* __restrict__ b_d,           // [H]
    const float* __restrict__ W_out,         // [1,H]
    const float* __restrict__ b_out,         // [1]
    float* __restrict__ out)                 // [B]
{
    const int b   = blockIdx.x;
    const int t   = threadIdx.x;
    const int g   = t >> 2;     // 0..127
    const int sub = t & 3;      // 0..3

    __shared__ _Float16 sh_h[2][160];
    __shared__ float    sh_c[2][144];
    __shared__ half2_t  sh_x2[2][32];
    __shared__ float    sh_red[HH];

    // ---- weights into registers via volatile loads (no re-load possible) ----
    half2_t wg[4][16];
    half2_t ug[4][8];
    float   wd[32];
    float   bq[4];
    {
        #pragma unroll
        for (int q = 0; q < 4; ++q) {
            const int row = g + 128 * q;
            const volatile float4* p =
                (const volatile float4*)(W_all + (size_t)row * HH + 32 * sub);
            #pragma unroll
            for (int i = 0; i < 8; ++i) {
                float4 v; v.x = p[i].x; v.y = p[i].y; v.z = p[i].z; v.w = p[i].w;
                half2_t h0, h1;
                h0.x = (_Float16)v.x; h0.y = (_Float16)v.y;
                h1.x = (_Float16)v.z; h1.y = (_Float16)v.w;
                wg[q][2*i]   = h0;
                wg[q][2*i+1] = h1;
            }
            const volatile float4* pu =
                (const volatile float4*)(U_all + (size_t)row * EE + 16 * sub);
            #pragma unroll
            for (int i = 0; i < 4; ++i) {
                float4 v; v.x = pu[i].x; v.y = pu[i].y; v.z = pu[i].z; v.w = pu[i].w;
                half2_t h0, h1;
                h0.x = (_Float16)v.x; h0.y = (_Float16)v.y;
                h1.x = (_Float16)v.z; h1.y = (_Float16)v.w;
                ug[q][2*i]   = h0;
                ug[q][2*i+1] = h1;
            }
            bq[q] = b_all[row] + b_u[row];
        }
        const volatile float4* p =
            (const volatile float4*)(W_d + (size_t)g * HH + 32 * sub);
        #pragma unroll
        for (int i = 0; i < 8; ++i) {
            float4 v; v.x = p[i].x; v.y = p[i].y; v.z = p[i].z; v.w = p[i].w;
            wd[4*i] = v.x; wd[4*i+1] = v.y; wd[4*i+2] = v.z; wd[4*i+3] = v.w;
        }
    }
    #pragma unroll
    for (int q = 0; q < 4; ++q) {
        #pragma unroll
        for (int i = 0; i < 16; ++i) asm volatile("" : "+v"(wg[q][i]));
        #pragma unroll
        for (int i = 0; i < 8; ++i)  asm volatile("" : "+v"(ug[q][i]));
    }
    #pragma unroll
    for (int i = 0; i < 32; ++i) asm volatile("" : "+v"(wd[i]));

    const float bd_r = b_d[g];

    const float* xb   = inputs + (size_t)b * SS * EE;
    const float* drow = time_interval + (size_t)b * SS;

    // ---- prologue: zero FULL padded h buffer, c buffer; prime x pipeline ----
    if (t < 160) sh_h[0][t] = (_Float16)0.f;          // all 160 slots incl. pads
    if (t < HH)  sh_c[0][CPAD(t)] = 0.f;
    float xcv = 0.f, xld = 0.f;
    if (t < 64) {
        ((_Float16*)sh_x2[0])[t] = (_Float16)xb[t];   // x[0]
        xcv = xb[EE + t];                              // x[1]
        xld = xb[2 * EE + t];                          // x[2]
    }
    float dv0 = drow[0], dv1 = drow[1], dv2 = drow[2];
    float hsum = 0.f;
    __syncthreads();

#define TLSTM_STEP(s, CUR, NXT)                                               \
    {                                                                         \
        if (t < 64) {                                                         \
            ((_Float16*)sh_x2[NXT])[t] = (_Float16)xcv;                       \
            xcv = xld;                                                        \
            const int s3 = ((s) + 3 < SS) ? (s) + 3 : SS - 1;                 \
            xld = xb[(size_t)s3 * EE + t];                                    \
        }                                                                     \
        float a0 = 0.f, a1 = 0.f, a2 = 0.f, a3 = 0.f, ad = 0.f;               \
        {                                                                     \
            const half2_t* hp = (const half2_t*)&sh_h[CUR][40 * sub];         \
            _Pragma("unroll")                                                 \
            for (int i = 0; i < 16; ++i) {                                    \
                half2_t hv = hp[i];                                           \
                a0 = dot2f(wg[0][i], hv, a0);                                 \
                a1 = dot2f(wg[1][i], hv, a1);                                 \
                a2 = dot2f(wg[2][i], hv, a2);                                 \
                a3 = dot2f(wg[3][i], hv, a3);                                 \
            }                                                                 \
            const half2_t* xp2 = &sh_x2[CUR][8 * sub];                        \
            _Pragma("unroll")                                                 \
            for (int i = 0; i < 8; ++i) {                                     \
                half2_t xv = xp2[i];                                          \
                a0 = dot2f(ug[0][i], xv, a0);                                 \
                a1 = dot2f(ug[1][i], xv, a1);                                 \
                a2 = dot2f(ug[2][i], xv, a2);                                 \
                a3 = dot2f(ug[3][i], xv, a3);                                 \
            }                                                                 \
            const float4* cp = (const float4*)&sh_c[CUR][36 * sub];           \
            _Pragma("unroll")                                                 \
            for (int i = 0; i < 8; ++i) {                                     \
                float4 cv = cp[i];                                            \
                ad += wd[4*i]*cv.x + wd[4*i+1]*cv.y                           \
                    + wd[4*i+2]*cv.z + wd[4*i+3]*cv.w;                        \
            }                                                                 \
        }                                                                     \
        a0 += __shfl_xor(a0, 1); a1 += __shfl_xor(a1, 1);                     \
        a2 += __shfl_xor(a2, 1); a3 += __shfl_xor(a3, 1);                     \
        ad += __shfl_xor(ad, 1);                                              \
        a0 += __shfl_xor(a0, 2); a1 += __shfl_xor(a1, 2);                     \
        a2 += __shfl_xor(a2, 2); a3 += __shfl_xor(a3, 2);                     \
        ad += __shfl_xor(ad, 2);                                              \
        float c_old = sh_c[CUR][CPAD(g)];                                     \
        float cs1   = fast_tanh(bd_r + ad);                                   \
        float c_adj = c_old + cs1 * (dv0 - 1.0f);                             \
        float f  = fast_sigmoid(a0 + bq[0]);                                  \
        float ii = fast_sigmoid(a1 + bq[1]);                                  \
        float o  = fast_sigmoid(a2 + bq[2]);                                  \
        float ct = fast_sigmoid(a3 + bq[3]);                                  \
        float cn = f * c_adj + ii * ct;                                       \
        float hn = o * fast_tanh(cn);                                         \
        if (sub == 0) {                                                       \
            sh_c[NXT][CPAD(g)] = cn;                                          \
            sh_h[NXT][HPADW(g)] = (_Float16)hn;                               \
        }                                                                     \
        hsum += hn;                                                           \
        dv0 = dv1; dv1 = dv2;                                                 \
        const int sd = ((s) + 3 < SS) ? (s) + 3 : SS - 1;                     \
        dv2 = drow[sd];                                                       \
        __syncthreads();                                                      \
    }

    for (int s = 0; s < SS; s += 2) {
        TLSTM_STEP(s,     0, 1)
        TLSTM_STEP(s + 1, 1, 0)
    }
#undef TLSTM_STEP

    // ---- output epilogue: out[b] = (sum_s h_s) . W_out + S*b_out ----
    if (sub == 0) sh_red[g] = hsum * W_out[g];
    __syncthreads();
    if (t == 0) {
        float acc = 0.f;
        for (int i = 0; i < HH; ++i) acc += sh_red[i];
        out[b] = acc + (float)SS * b_out[0];
    }
}

extern "C" void kernel_launch(void* const* d_in, const int* in_sizes, int n_in,
                              void* d_out, int out_size, void* d_ws, size_t ws_size,
                              hipStream_t stream) {
    const float* inputs        = (const float*)d_in[0];
    const float* time_interval = (const float*)d_in[1];
    const float* W_all         = (const float*)d_in[2];
    const float* b_all         = (const float*)d_in[3];
    const float* U_all         = (const float*)d_in[4];
    const float* b_u           = (const float*)d_in[5];
    const float* W_d           = (const float*)d_in[6];
    const float* b_d           = (const float*)d_in[7];
    const float* W_out         = (const float*)d_in[8];
    const float* b_out         = (const float*)d_in[9];
    float* out = (float*)d_out;

    tlstm_fused3_kernel<<<dim3(BB), dim3(512), 0, stream>>>(
        inputs, time_interval, W_all, b_all, U_all, b_u,
        W_d, b_d, W_out, b_out, out);
}

// Round 7
// 2220.406 us; speedup vs baseline: 2.5105x; 1.2107x over previous
//
#include <hip/hip_runtime.h>
#include <math.h>

#define BB 256
#define SS 2048
#define EE 64
#define HH 128

typedef _Float16 half2_t __attribute__((ext_vector_type(2)));

#if defined(__has_builtin)
#if __has_builtin(__builtin_amdgcn_fdot2)
#define HAVE_FDOT2 1
#endif
#if __has_builtin(__builtin_amdgcn_update_dpp)
#define HAVE_DPP 1
#endif
#endif

__device__ __forceinline__ float dot2f(half2_t a, half2_t b, float c) {
#ifdef HAVE_FDOT2
    return __builtin_amdgcn_fdot2(a, b, c, false);
#else
    return c + (float)a.x * (float)b.x + (float)a.y * (float)b.y;
#endif
}

// sum over the 4-lane quad: XOR-1 then XOR-2, both intra-quad -> DPP quad_perm
// (VALU, no DS-pipe traffic). 0xB1 = quad_perm[1,0,3,2], 0x4E = quad_perm[2,3,0,1].
__device__ __forceinline__ float qsum(float v) {
#ifdef HAVE_DPP
    int s1 = __builtin_amdgcn_update_dpp(0, __float_as_int(v), 0xB1, 0xF, 0xF, true);
    v += __int_as_float(s1);
    int s2 = __builtin_amdgcn_update_dpp(0, __float_as_int(v), 0x4E, 0xF, 0xF, true);
    v += __int_as_float(s2);
#else
    v += __shfl_xor(v, 1);
    v += __shfl_xor(v, 2);
#endif
    return v;
}

__device__ __forceinline__ float fast_sigmoid(float x) {
    return 1.0f / (1.0f + __expf(-x));
}
__device__ __forceinline__ float fast_tanh(float x) {
    x = fminf(15.0f, fmaxf(-15.0f, x));
    float e = __expf(2.0f * x);
    return (e - 1.0f) / (e + 1.0f);
}

// h / c2 layout: 32-elem slices at 48-half (96 B) stride.
// 96 B is 16B-aligned -> ds_read_b128; slice bases hit dword-banks 0/24/16/8.
#define HIDX(k) (((k) & 31) + 48 * ((k) >> 5))

// One block per batch element, 512 threads, single dispatch.
// 4-lane group per hidden unit g = t>>2, sub = t&3 owning k-slice [32*sub,+32).
// Per lane (registers/AGPRs): wg[4][16] (W_all, fp16), ug[4][8] (U_all, fp16),
// wdh[16] (W_d, fp16). fp32 c carry lives in a REGISTER (all 4 lanes compute
// cn redundantly after the quad reduction) -> no fp32 c LDS round-trip.
// LDS per step per lane: 4+4+2 ds_read_b128, ~2 b16 writes (sub0), 1 barrier.
__global__ __launch_bounds__(512, 2) void tlstm_fused4_kernel(
    const float* __restrict__ inputs,        // [B,S,E]
    const float* __restrict__ time_interval, // [B,S]
    const float* __restrict__ W_all,         // [4H,H]
    const float* __restrict__ b_all,         // [4H]
    const float* __restrict__ U_all,         // [4H,E]
    const float* __restrict__ b_u,           // [4H]
    const float* __restrict__ W_d,           // [H,H]
    const float* __restrict__ b_d,           // [H]
    const float* __restrict__ W_out,         // [1,H]
    const float* __restrict__ b_out,         // [1]
    float* __restrict__ out)                 // [B]
{
    const int b   = blockIdx.x;
    const int t   = threadIdx.x;
    const int g   = t >> 2;     // 0..127
    const int sub = t & 3;      // 0..3

    __shared__ __align__(16) _Float16 sh_h[2][192];   // h, fp16, padded
    __shared__ __align__(16) _Float16 sh_c2[2][192];  // c, fp16 copy for W_d dot
    __shared__ __align__(16) half2_t  sh_x2[2][32];   // x row, fp16
    __shared__ float sh_red[HH];

    // ---- weights into registers (fp16-packed), pinned ----
    half2_t wg[4][16];   // W_all rows {g,g+128,g+256,g+384}, k in [32*sub,+32)
    half2_t ug[4][8];    // U_all rows (same), e in [16*sub,+16)
    half2_t wdh[16];     // W_d row g, k in [32*sub,+32)
    float   bq[4];
    {
        #pragma unroll
        for (int q = 0; q < 4; ++q) {
            const int row = g + 128 * q;
            const float4* p = (const float4*)(W_all + (size_t)row * HH + 32 * sub);
            #pragma unroll
            for (int i = 0; i < 8; ++i) {
                float4 v = p[i];
                half2_t h0, h1;
                h0.x = (_Float16)v.x; h0.y = (_Float16)v.y;
                h1.x = (_Float16)v.z; h1.y = (_Float16)v.w;
                wg[q][2*i]   = h0;
                wg[q][2*i+1] = h1;
            }
            const float4* pu = (const float4*)(U_all + (size_t)row * EE + 16 * sub);
            #pragma unroll
            for (int i = 0; i < 4; ++i) {
                float4 v = pu[i];
                half2_t h0, h1;
                h0.x = (_Float16)v.x; h0.y = (_Float16)v.y;
                h1.x = (_Float16)v.z; h1.y = (_Float16)v.w;
                ug[q][2*i]   = h0;
                ug[q][2*i+1] = h1;
            }
            bq[q] = b_all[row] + b_u[row];
        }
        const float4* p = (const float4*)(W_d + (size_t)g * HH + 32 * sub);
        #pragma unroll
        for (int i = 0; i < 8; ++i) {
            float4 v = p[i];
            half2_t h0, h1;
            h0.x = (_Float16)v.x; h0.y = (_Float16)v.y;
            h1.x = (_Float16)v.z; h1.y = (_Float16)v.w;
            wdh[2*i]   = h0;
            wdh[2*i+1] = h1;
        }
    }
    #pragma unroll
    for (int q = 0; q < 4; ++q) {
        #pragma unroll
        for (int i = 0; i < 16; ++i) asm volatile("" : "+v"(wg[q][i]));
        #pragma unroll
        for (int i = 0; i < 8; ++i)  asm volatile("" : "+v"(ug[q][i]));
    }
    #pragma unroll
    for (int i = 0; i < 16; ++i) asm volatile("" : "+v"(wdh[i]));

    const float bd_r = b_d[g];

    const float* xb   = inputs + (size_t)b * SS * EE;
    const float* drow = time_interval + (size_t)b * SS;

    // ---- prologue: zero buffer 0 (incl. pads), prime x pipeline ----
    if (t < 192) { sh_h[0][t] = (_Float16)0.f; sh_c2[0][t] = (_Float16)0.f; }
    float xcv = 0.f, xld = 0.f;
    if (t < 64) {
        ((_Float16*)sh_x2[0])[t] = (_Float16)xb[t];   // x[0]
        xcv = xb[EE + t];                              // x[1]
        xld = xb[2 * EE + t];                          // x[2]
    }
    float dv0 = drow[0], dv1 = drow[1], dv2 = drow[2];
    float hsum = 0.f;
    float c_keep = 0.f;   // fp32 cell state, register-resident (redundant x4 lanes)
    __syncthreads();

#define TLSTM_STEP(s, CUR, NXT)                                               \
    {                                                                         \
        if (t < 64) {                                                         \
            ((_Float16*)sh_x2[NXT])[t] = (_Float16)xcv;                       \
            xcv = xld;                                                        \
            const int s3 = ((s) + 3 < SS) ? (s) + 3 : SS - 1;                 \
            xld = xb[(size_t)s3 * EE + t];                                    \
        }                                                                     \
        float a0 = 0.f, a1 = 0.f, a2 = 0.f, a3 = 0.f, ad = 0.f;               \
        {                                                                     \
            const float4* hp =                                                \
                (const float4*)((const _Float16*)sh_h[CUR] + 48 * sub);       \
            _Pragma("unroll")                                                 \
            for (int i = 0; i < 4; ++i) {                                     \
                float4 hv4 = hp[i];                                           \
                const half2_t* hh = (const half2_t*)&hv4;                     \
                _Pragma("unroll")                                             \
                for (int j = 0; j < 4; ++j) {                                 \
                    half2_t hv = hh[j];                                       \
                    a0 = dot2f(wg[0][4*i+j], hv, a0);                         \
                    a1 = dot2f(wg[1][4*i+j], hv, a1);                         \
                    a2 = dot2f(wg[2][4*i+j], hv, a2);                         \
                    a3 = dot2f(wg[3][4*i+j], hv, a3);                         \
                }                                                             \
            }                                                                 \
            const float4* xp4 =                                               \
                (const float4*)((const half2_t*)sh_x2[CUR] + 8 * sub);        \
            _Pragma("unroll")                                                 \
            for (int i = 0; i < 2; ++i) {                                     \
                float4 xv4 = xp4[i];                                          \
                const half2_t* xh = (const half2_t*)&xv4;                     \
                _Pragma("unroll")                                             \
                for (int j = 0; j < 4; ++j) {                                 \
                    half2_t xv = xh[j];                                       \
                    a0 = dot2f(ug[0][4*i+j], xv, a0);                         \
                    a1 = dot2f(ug[1][4*i+j], xv, a1);                         \
                    a2 = dot2f(ug[2][4*i+j], xv, a2);                         \
                    a3 = dot2f(ug[3][4*i+j], xv, a3);                         \
                }                                                             \
            }                                                                 \
            const float4* cp =                                                \
                (const float4*)((const _Float16*)sh_c2[CUR] + 48 * sub);      \
            _Pragma("unroll")                                                 \
            for (int i = 0; i < 4; ++i) {                                     \
                float4 cv4 = cp[i];                                           \
                const half2_t* ch = (const half2_t*)&cv4;                     \
                _Pragma("unroll")                                             \
                for (int j = 0; j < 4; ++j)                                   \
                    ad = dot2f(wdh[4*i+j], ch[j], ad);                        \
            }                                                                 \
        }                                                                     \
        a0 = qsum(a0); a1 = qsum(a1); a2 = qsum(a2); a3 = qsum(a3);           \
        ad = qsum(ad);                                                        \
        float cs1   = fast_tanh(bd_r + ad);                                   \
        float c_adj = c_keep + cs1 * (dv0 - 1.0f);                            \
        float f  = fast_sigmoid(a0 + bq[0]);                                  \
        float ii = fast_sigmoid(a1 + bq[1]);                                  \
        float o  = fast_sigmoid(a2 + bq[2]);                                  \
        float ct = fast_sigmoid(a3 + bq[3]);                                  \
        float cn = f * c_adj + ii * ct;                                       \
        float hn = o * fast_tanh(cn);                                         \
        c_keep = cn;                                                          \
        if (sub == 0) {                                                       \
            ((_Float16*)sh_c2[NXT])[HIDX(g)] = (_Float16)cn;                  \
            ((_Float16*)sh_h[NXT])[HIDX(g)]  = (_Float16)hn;                  \
        }                                                                     \
        hsum += hn;                                                           \
        dv0 = dv1; dv1 = dv2;                                                 \
        const int sd = ((s) + 3 < SS) ? (s) + 3 : SS - 1;                     \
        dv2 = drow[sd];                                                       \
        __syncthreads();                                                      \
    }

    for (int s = 0; s < SS; s += 2) {
        TLSTM_STEP(s,     0, 1)
        TLSTM_STEP(s + 1, 1, 0)
    }
#undef TLSTM_STEP

    // ---- output epilogue: out[b] = (sum_s h_s) . W_out + S*b_out ----
    if (sub == 0) sh_red[g] = hsum * W_out[g];
    __syncthreads();
    if (t == 0) {
        float acc = 0.f;
        for (int i = 0; i < HH; ++i) acc += sh_red[i];
        out[b] = acc + (float)SS * b_out[0];
    }
}

extern "C" void kernel_launch(void* const* d_in, const int* in_sizes, int n_in,
                              void* d_out, int out_size, void* d_ws, size_t ws_size,
                              hipStream_t stream) {
    const float* inputs        = (const float*)d_in[0];
    const float* time_interval = (const float*)d_in[1];
    const float* W_all         = (const float*)d_in[2];
    const float* b_all         = (const float*)d_in[3];
    const float* U_all         = (const float*)d_in[4];
    const float* b_u           = (const float*)d_in[5];
    const float* W_d           = (const float*)d_in[6];
    const float* b_d           = (const float*)d_in[7];
    const float* W_out         = (const float*)d_in[8];
    const float* b_out         = (const float*)d_in[9];
    float* out = (float*)d_out;

    tlstm_fused4_kernel<<<dim3(BB), dim3(512), 0, stream>>>(
        inputs, time_interval, W_all, b_all, U_all, b_u,
        W_d, b_d, W_out, b_out, out);
}